// Round 8
// baseline (180.742 us; speedup 1.0000x reference)
//
#include <hip/hip_runtime.h>
#include <hip/hip_bf16.h>

// loss = mean_n( logsumexp([pos_n, (online@queue)_n]/t) - pos_n/t )   (fwd: alpha mix = identity)
// v8 = v7 with occupancy fix: BN=64 stripes (32 KB LDS -> 4 blocks/CU, 16 waves/CU),
//     wave tile 64x64, acc[4][4], launch_bounds(256,4). 1024 blocks = exactly 4/CU.

#define NROWS 1024
#define DDIM  256
#define KQ    65536
#define BN    64
#define NPART 1024
#define LN2_F 0.69314718055994531f

typedef short  short8  __attribute__((ext_vector_type(8)));
typedef float  floatx4 __attribute__((ext_vector_type(4)));

__device__ __forceinline__ unsigned short f2bf(float f) {
    unsigned int u = __float_as_uint(f);
    u += 0x7FFFu + ((u >> 16) & 1u);   // RNE
    return (unsigned short)(u >> 16);
}

// ---- A conversion (bf16(A/(t*ln2))) + fused positive-pair dot (one wave per row) ----
__global__ __launch_bounds__(256)
void conv_a(const float* __restrict__ A, const float* __restrict__ mom,
            const float* __restrict__ temp,
            unsigned short* __restrict__ Ab, float* __restrict__ pos2)
{
    const float s = 1.0f / (temp[0] * LN2_F);
    const int i = blockIdx.x * 256 + threadIdx.x;       // global float4 index, 64 per row
    const floatx4 v = ((const floatx4*)A)[i];
    ushort4 w;
    w.x = f2bf(v.x * s); w.y = f2bf(v.y * s);
    w.z = f2bf(v.z * s); w.w = f2bf(v.w * s);
    ((ushort4*)Ab)[i] = w;

    const floatx4 m = ((const floatx4*)mom)[i];
    float d = v.x * m.x + v.y * m.y + v.z * m.z + v.w * m.w;
    d += __shfl_xor(d, 1, 64);
    d += __shfl_xor(d, 2, 64);
    d += __shfl_xor(d, 4, 64);
    d += __shfl_xor(d, 8, 64);
    d += __shfl_xor(d, 16, 64);
    d += __shfl_xor(d, 32, 64);
    if ((threadIdx.x & 63) == 0)
        pos2[i >> 6] = d * s;          // base-2-domain positive logit
}

// ---- fused GEMM + online-softmax partials. 1024 blocks x 256 thr; block = one 64-col stripe ----
__global__ __launch_bounds__(256, 4)
void gemm_softmax(const unsigned short* __restrict__ Ab,   // [1024][256] bf16, pre-scaled
                  const float* __restrict__ Q,             // [256][65536] fp32
                  float2* __restrict__ partials)           // [NPART][1024]  (part-major)
{
    __shared__ __align__(16) unsigned short Bl[BN * DDIM];   // [n][k] bf16, 32 KB, swizzled

    const int tid  = threadIdx.x;
    const int lane = tid & 63;
    const int wave = tid >> 6;          // 0..3 (row bands)
    const int l15  = lane & 15;
    const int quad = lane >> 4;
    const int nb   = blockIdx.x;        // 0..1023
    const int nbase = nb * BN;

    // ---- stage B once: Q[k][nbase..+63] fp32 -> Bl[n][k] bf16 (register transpose) ----
    #pragma unroll
    for (int iter = 0; iter < 2; ++iter) {
        const int t2 = iter * 256 + tid;    // 512 tasks
        const int ny = t2 & 15;             // n-quad (4 cols)
        const int ko = t2 >> 4;             // k-octet (8 rows), 0..31
        floatx4 v[8];
        #pragma unroll
        for (int j = 0; j < 8; ++j)
            v[j] = __builtin_nontemporal_load(
                       (const floatx4*)(Q + (size_t)(ko * 8 + j) * KQ + nbase + ny * 4));
        #pragma unroll
        for (int i2 = 0; i2 < 4; ++i2) {
            const int n = ny * 4 + i2;
            const int phys = ko ^ (n & 15);      // 16B-chunk XOR swizzle (32 chunks/row)
            short8 w;
            #pragma unroll
            for (int j = 0; j < 8; ++j)
                w[j] = (short)f2bf(v[j][i2]);
            *(short8*)&Bl[n * DDIM + phys * 8] = w;
        }
    }
    __syncthreads();   // the ONLY barrier

    #pragma unroll 1
    for (int g = 0; g < 4; ++g) {
        const int rowbase = g * 256 + wave * 64;
        const unsigned short* apb = Ab + (size_t)(rowbase + l15) * DDIM + quad * 8;

        floatx4 acc[4][4] = {};

        #pragma unroll 2
        for (int s = 0; s < 8; ++s) {
            short8 af[4];
            #pragma unroll
            for (int i = 0; i < 4; ++i)
                af[i] = *(const short8*)(apb + i * 16 * DDIM + s * 32);

            const int vb = l15 * 512 + (((4 * s + quad) ^ l15) * 16);
            short8 bfv[4];
            #pragma unroll
            for (int j = 0; j < 4; ++j)
                bfv[j] = *(const short8*)((const char*)Bl + vb + j * 8192);

            #pragma unroll
            for (int i = 0; i < 4; ++i)
                #pragma unroll
                for (int j = 0; j < 4; ++j)
                    acc[i][j] = __builtin_amdgcn_mfma_f32_16x16x32_bf16(af[i], bfv[j], acc[i][j], 0, 0, 0);
        }

        // epilogue: base-2 logits. C layout: col(n) = lane&15, row(m) = quad*4+reg (verified).
        #pragma unroll
        for (int i = 0; i < 4; ++i) {
            float2 tmp[4];
            #pragma unroll
            for (int r = 0; r < 4; ++r) {
                float mx = fmaxf(fmaxf(acc[i][0][r], acc[i][1][r]),
                                 fmaxf(acc[i][2][r], acc[i][3][r]));
                mx = fmaxf(mx, __shfl_xor(mx, 1, 64));
                mx = fmaxf(mx, __shfl_xor(mx, 2, 64));
                mx = fmaxf(mx, __shfl_xor(mx, 4, 64));
                mx = fmaxf(mx, __shfl_xor(mx, 8, 64));
                float s2 = 0.f;
                #pragma unroll
                for (int j = 0; j < 4; ++j)
                    s2 += __builtin_amdgcn_exp2f(acc[i][j][r] - mx);
                s2 += __shfl_xor(s2, 1, 64);
                s2 += __shfl_xor(s2, 2, 64);
                s2 += __shfl_xor(s2, 4, 64);
                s2 += __shfl_xor(s2, 8, 64);
                tmp[r] = make_float2(mx, s2);
            }
            if (l15 == 0) {
                // 4 quad-leader lanes cover 128 contiguous bytes
                const int row = rowbase + i * 16 + quad * 4;
                floatx4* dst = (floatx4*)(partials + (size_t)nb * NROWS + row);
                floatx4 w0 = {tmp[0].x, tmp[0].y, tmp[1].x, tmp[1].y};
                floatx4 w1 = {tmp[2].x, tmp[2].y, tmp[3].x, tmp[3].y};
                __builtin_nontemporal_store(w0, dst);
                __builtin_nontemporal_store(w1, dst + 1);
            }
        }
    }
}

// ---- combine partials per row + positive logit + atomic mean ----
// Grid: 64 blocks x 256 threads. Block owns 16 rows; 16 part-groups of 64 parts.
__global__ __launch_bounds__(256)
void finalize_rows(const float2* __restrict__ partials,   // [NPART][1024]
                   const float* __restrict__ pos2,
                   float* __restrict__ out)
{
    const int t   = threadIdx.x;
    const int rl  = t & 15;              // row within block
    const int grp = t >> 4;              // part group 0..15
    const int row = blockIdx.x * 16 + rl;

    float M = -3.0e38f, S = 0.f;
    #pragma unroll 1
    for (int pb = 0; pb < 64; pb += 8) {
        float2 v[8];
        #pragma unroll
        for (int j = 0; j < 8; ++j)
            v[j] = partials[(size_t)(grp * 64 + pb + j) * NROWS + row];
        #pragma unroll
        for (int j = 0; j < 8; ++j) {
            const float M2 = fmaxf(M, v[j].x);
            S = S * __builtin_amdgcn_exp2f(M - M2) + v[j].y * __builtin_amdgcn_exp2f(v[j].x - M2);
            M = M2;
        }
    }

    __shared__ float2 sm[16][17];
    sm[grp][rl] = make_float2(M, S);
    __syncthreads();

    if (t < 64) {
        float val = 0.f;
        if (t < 16) {
            float Mm = -3.0e38f, Ss = 0.f;
            #pragma unroll
            for (int g2 = 0; g2 < 16; ++g2) {
                const float2 v = sm[g2][t];
                const float M2 = fmaxf(Mm, v.x);
                Ss = Ss * __builtin_amdgcn_exp2f(Mm - M2) + v.y * __builtin_amdgcn_exp2f(v.x - M2);
                Mm = M2;
            }
            const float p  = pos2[blockIdx.x * 16 + t];
            const float M2 = fmaxf(Mm, p);
            const float L  = Ss * __builtin_amdgcn_exp2f(Mm - M2) + __builtin_amdgcn_exp2f(p - M2);
            val = (M2 + __builtin_amdgcn_logf(L) - p) * LN2_F;   // back to natural log
        }
        val += __shfl_xor(val, 1, 64);
        val += __shfl_xor(val, 2, 64);
        val += __shfl_xor(val, 4, 64);
        val += __shfl_xor(val, 8, 64);
        val += __shfl_xor(val, 16, 64);
        val += __shfl_xor(val, 32, 64);
        if (t == 0) atomicAdd(out, val * (1.0f / (float)NROWS));
    }
}

extern "C" void kernel_launch(void* const* d_in, const int* in_sizes, int n_in,
                              void* d_out, int out_size, void* d_ws, size_t ws_size,
                              hipStream_t stream)
{
    const float* online = (const float*)d_in[0];   // [1024][256]
    const float* mom    = (const float*)d_in[1];   // [1024][256]
    const float* queue  = (const float*)d_in[2];   // [256][65536]
    const float* temp   = (const float*)d_in[3];   // [1]
    float* out = (float*)d_out;

    // ws: Ab bf16 [1024][256] (512 KB) | partials float2 [1024][1024] (8 MB) | pos2 [1024] (4 KB)
    char* ws = (char*)d_ws;
    unsigned short* Ab = (unsigned short*)ws;
    float2* partials   = (float2*)(ws + 524288);
    float*  pos2       = (float*)(ws + 524288 + 8388608);

    (void)hipMemsetAsync(out, 0, sizeof(float), stream);
    conv_a<<<256, 256, 0, stream>>>(online, mom, temp, Ab, pos2);
    gemm_softmax<<<KQ / BN, 256, 0, stream>>>(Ab, queue, partials);
    finalize_rows<<<64, 256, 0, stream>>>(partials, pos2, out);
}

// Round 9
// 150.921 us; speedup vs baseline: 1.1976x; 1.1976x over previous
//
#include <hip/hip_runtime.h>
#include <hip/hip_bf16.h>

// loss = mean_n( logsumexp([pos_n, (online@queue)_n]/t) - pos_n/t )   (fwd: alpha mix = identity)
// v9 = v7 geometry (BN=128, 2 blocks/CU) + full A/B register ping-pong prefetch,
//      DPP-based epilogue reductions (no LDS-pipe shfls), 3 graph nodes
//      (memset folded into conv_a, pos-dot folded into finalize).

#define NROWS 1024
#define DDIM  256
#define KQ    65536
#define BN    128
#define NPART 512
#define LN2_F 0.69314718055994531f

typedef short  short8  __attribute__((ext_vector_type(8)));
typedef float  floatx4 __attribute__((ext_vector_type(4)));

__device__ __forceinline__ unsigned short f2bf(float f) {
    unsigned int u = __float_as_uint(f);
    u += 0x7FFFu + ((u >> 16) & 1u);   // RNE
    return (unsigned short)(u >> 16);
}

// DPP lane-permute (row-of-16 scope). quad_perm xor1=0xB1, xor2=0x4E,
// row_half_mirror=0x141 (pairs quads), row_mirror=0x140 (pairs octets).
#define DPPMOV(x, ctrl) \
    __uint_as_float(__builtin_amdgcn_mov_dpp(__float_as_uint(x), (ctrl), 0xF, 0xF, true))

__device__ __forceinline__ float dpp16_max(float x) {
    x = fmaxf(x, DPPMOV(x, 0xB1));
    x = fmaxf(x, DPPMOV(x, 0x4E));
    x = fmaxf(x, DPPMOV(x, 0x141));
    x = fmaxf(x, DPPMOV(x, 0x140));
    return x;   // all 16 lanes of the row-of-16 hold the max
}
__device__ __forceinline__ float dpp16_sum(float x) {
    x += DPPMOV(x, 0xB1);
    x += DPPMOV(x, 0x4E);
    x += DPPMOV(x, 0x141);
    x += DPPMOV(x, 0x140);
    return x;
}

// ---- A conversion: bf16(A/(t*ln2)); also zeroes the output accumulator ----
__global__ __launch_bounds__(256)
void conv_a(const float* __restrict__ A, const float* __restrict__ temp,
            unsigned short* __restrict__ Ab, float* __restrict__ out)
{
    if (blockIdx.x == 0 && threadIdx.x == 0) out[0] = 0.0f;
    const float s = 1.0f / (temp[0] * LN2_F);
    const int i = blockIdx.x * 256 + threadIdx.x;       // 65536 threads, one float4 each
    const floatx4 v = ((const floatx4*)A)[i];
    ushort4 w;
    w.x = f2bf(v.x * s); w.y = f2bf(v.y * s);
    w.z = f2bf(v.z * s); w.w = f2bf(v.w * s);
    ((ushort4*)Ab)[i] = w;
}

// ---- fused GEMM + online-softmax partials. 512 blocks x 256 thr; block = one 128-col stripe ----
__global__ __launch_bounds__(256, 2)
void gemm_softmax(const unsigned short* __restrict__ Ab,   // [1024][256] bf16, pre-scaled
                  const float* __restrict__ Q,             // [256][65536] fp32
                  float2* __restrict__ partials)           // [NPART][1024]  (part-major)
{
    __shared__ __align__(16) unsigned short Bl[BN * DDIM];   // [n][k] bf16, 64 KB, swizzled

    const int tid  = threadIdx.x;
    const int lane = tid & 63;
    const int wave = tid >> 6;          // 0..3 (row bands)
    const int l15  = lane & 15;
    const int quad = lane >> 4;
    const int nb   = blockIdx.x;        // 0..511
    const int nbase = nb * BN;

    // ---- stage B once: Q[k][nbase..+127] fp32 -> Bl[n][k] bf16 (register transpose) ----
    #pragma unroll
    for (int iter = 0; iter < 4; ++iter) {
        const int t2 = iter * 256 + tid;    // 1024 tasks
        const int ny = t2 & 31;             // n-quad (4 cols)
        const int ko = t2 >> 5;             // k-octet (8 rows), 0..31
        floatx4 v[8];
        #pragma unroll
        for (int j = 0; j < 8; ++j)
            v[j] = __builtin_nontemporal_load(
                       (const floatx4*)(Q + (size_t)(ko * 8 + j) * KQ + nbase + ny * 4));
        #pragma unroll
        for (int i2 = 0; i2 < 4; ++i2) {
            const int n = ny * 4 + i2;
            const int phys = ko ^ (n & 15);      // 16B-chunk XOR swizzle
            short8 w;
            #pragma unroll
            for (int j = 0; j < 8; ++j)
                w[j] = (short)f2bf(v[j][i2]);
            *(short8*)&Bl[n * DDIM + phys * 8] = w;
        }
    }
    __syncthreads();   // the ONLY barrier

    #pragma unroll 1
    for (int g = 0; g < 4; ++g) {
        const int rowbase = g * 256 + wave * 64;
        const unsigned short* apb = Ab + (size_t)(rowbase + l15) * DDIM + quad * 8;

        floatx4 acc[4][8] = {};
        short8 afA[4], afB[4], bfA[8], bfB[8];

        // prologue: s=0 fragments
        #pragma unroll
        for (int i = 0; i < 4; ++i)
            afA[i] = *(const short8*)(apb + i * 16 * DDIM);
        {
            const int vb = l15 * 512 + ((quad ^ l15) * 16);
            #pragma unroll
            for (int j = 0; j < 8; ++j)
                bfA[j] = *(const short8*)((const char*)Bl + vb + j * 8192);
        }

        #pragma unroll 1
        for (int sp = 0; sp < 4; ++sp) {
            const int s1 = 2 * sp + 1;
            // prefetch odd step
            #pragma unroll
            for (int i = 0; i < 4; ++i)
                afB[i] = *(const short8*)(apb + i * 16 * DDIM + s1 * 32);
            {
                const int vb = l15 * 512 + (((4 * s1 + quad) ^ l15) * 16);
                #pragma unroll
                for (int j = 0; j < 8; ++j)
                    bfB[j] = *(const short8*)((const char*)Bl + vb + j * 8192);
            }
            // compute even step
            #pragma unroll
            for (int i = 0; i < 4; ++i)
                #pragma unroll
                for (int j = 0; j < 8; ++j)
                    acc[i][j] = __builtin_amdgcn_mfma_f32_16x16x32_bf16(afA[i], bfA[j], acc[i][j], 0, 0, 0);

            const int s2 = (2 * sp + 2) & 7;   // 2,4,6,0 (sp==3 loads are dead; cheap)
            #pragma unroll
            for (int i = 0; i < 4; ++i)
                afA[i] = *(const short8*)(apb + i * 16 * DDIM + s2 * 32);
            {
                const int vb = l15 * 512 + (((4 * s2 + quad) ^ l15) * 16);
                #pragma unroll
                for (int j = 0; j < 8; ++j)
                    bfA[j] = *(const short8*)((const char*)Bl + vb + j * 8192);
            }
            // compute odd step
            #pragma unroll
            for (int i = 0; i < 4; ++i)
                #pragma unroll
                for (int j = 0; j < 8; ++j)
                    acc[i][j] = __builtin_amdgcn_mfma_f32_16x16x32_bf16(afB[i], bfB[j], acc[i][j], 0, 0, 0);
        }

        // epilogue: base-2 logits. C layout: col(n)=lane&15, row(m)=quad*4+reg (verified).
        #pragma unroll
        for (int i = 0; i < 4; ++i) {
            float2 tmp[4];
            #pragma unroll
            for (int r = 0; r < 4; ++r) {
                float mx = acc[i][0][r];
                #pragma unroll
                for (int j = 1; j < 8; ++j) mx = fmaxf(mx, acc[i][j][r]);
                mx = dpp16_max(mx);
                float s2 = 0.f;
                #pragma unroll
                for (int j = 0; j < 8; ++j)
                    s2 += __builtin_amdgcn_exp2f(acc[i][j][r] - mx);
                s2 = dpp16_sum(s2);
                tmp[r] = make_float2(mx, s2);
            }
            if (l15 == 0) {
                // 4 quad-leader lanes cover 128 contiguous bytes
                const int row = rowbase + i * 16 + quad * 4;
                floatx4* dst = (floatx4*)(partials + (size_t)nb * NROWS + row);
                floatx4 w0 = {tmp[0].x, tmp[0].y, tmp[1].x, tmp[1].y};
                floatx4 w1 = {tmp[2].x, tmp[2].y, tmp[3].x, tmp[3].y};
                __builtin_nontemporal_store(w0, dst);
                __builtin_nontemporal_store(w1, dst + 1);
            }
        }
    }
}

// ---- combine partials per row + positive logit (computed inline) + atomic mean ----
// Grid: 64 blocks x 256 threads. Block owns 16 rows; 16 part-groups of 32 parts.
__global__ __launch_bounds__(256)
void finalize_rows(const float2* __restrict__ partials,   // [NPART][1024]
                   const float* __restrict__ online,
                   const float* __restrict__ mom,
                   const float* __restrict__ temp,
                   float* __restrict__ out)
{
    const int t = threadIdx.x;
    __shared__ float2 sm[16][17];
    __shared__ float sm_pos[16];

    // phase 1: positive-pair logit, 16 threads per row (rows r2 = t>>4)
    {
        const float s = 1.0f / (temp[0] * LN2_F);
        const int r2 = t >> 4, c2 = t & 15;
        const float* po = online + (size_t)(blockIdx.x * 16 + r2) * DDIM + c2 * 16;
        const float* pm = mom    + (size_t)(blockIdx.x * 16 + r2) * DDIM + c2 * 16;
        float d = 0.f;
        #pragma unroll
        for (int w = 0; w < 4; ++w) {
            const floatx4 a = *(const floatx4*)(po + w * 4);
            const floatx4 b = *(const floatx4*)(pm + w * 4);
            d += a.x * b.x + a.y * b.y + a.z * b.z + a.w * b.w;
        }
        d = dpp16_sum(d);
        if (c2 == 0) sm_pos[r2] = d * s;    // base-2-domain positive logit
    }

    // phase 2: combine negative partials; rl = row-in-block, grp = part group
    const int rl  = t & 15;
    const int grp = t >> 4;
    const int row = blockIdx.x * 16 + rl;

    float M = -3.0e38f, S = 0.f;
    #pragma unroll 1
    for (int pb = 0; pb < 32; pb += 8) {
        float2 v[8];
        #pragma unroll
        for (int j = 0; j < 8; ++j)
            v[j] = partials[(size_t)(grp * 32 + pb + j) * NROWS + row];
        #pragma unroll
        for (int j = 0; j < 8; ++j) {
            const float M2 = fmaxf(M, v[j].x);
            S = S * __builtin_amdgcn_exp2f(M - M2) + v[j].y * __builtin_amdgcn_exp2f(v[j].x - M2);
            M = M2;
        }
    }
    sm[grp][rl] = make_float2(M, S);
    __syncthreads();

    if (t < 64) {
        float val = 0.f;
        if (t < 16) {
            float Mm = -3.0e38f, Ss = 0.f;
            #pragma unroll
            for (int g2 = 0; g2 < 16; ++g2) {
                const float2 v = sm[g2][t];
                const float M2 = fmaxf(Mm, v.x);
                Ss = Ss * __builtin_amdgcn_exp2f(Mm - M2) + v.y * __builtin_amdgcn_exp2f(v.x - M2);
                Mm = M2;
            }
            const float p  = sm_pos[t];
            const float M2 = fmaxf(Mm, p);
            const float L  = Ss * __builtin_amdgcn_exp2f(Mm - M2) + __builtin_amdgcn_exp2f(p - M2);
            val = (M2 + __builtin_amdgcn_logf(L) - p) * LN2_F;   // back to natural log
        }
        val += __shfl_xor(val, 1, 64);
        val += __shfl_xor(val, 2, 64);
        val += __shfl_xor(val, 4, 64);
        val += __shfl_xor(val, 8, 64);
        val += __shfl_xor(val, 16, 64);
        val += __shfl_xor(val, 32, 64);
        if (t == 0) atomicAdd(out, val * (1.0f / (float)NROWS));
    }
}

extern "C" void kernel_launch(void* const* d_in, const int* in_sizes, int n_in,
                              void* d_out, int out_size, void* d_ws, size_t ws_size,
                              hipStream_t stream)
{
    const float* online = (const float*)d_in[0];   // [1024][256]
    const float* mom    = (const float*)d_in[1];   // [1024][256]
    const float* queue  = (const float*)d_in[2];   // [256][65536]
    const float* temp   = (const float*)d_in[3];   // [1]
    float* out = (float*)d_out;

    // ws: Ab bf16 [1024][256] (512 KB) | partials float2 [512][1024] (4 MB)
    char* ws = (char*)d_ws;
    unsigned short* Ab = (unsigned short*)ws;
    float2* partials   = (float2*)(ws + 524288);

    conv_a<<<256, 256, 0, stream>>>(online, temp, Ab, out);
    gemm_softmax<<<KQ / BN, 256, 0, stream>>>(Ab, queue, partials);
    finalize_rows<<<64, 256, 0, stream>>>(partials, online, mom, temp, out);
}